// Round 3
// baseline (665.660 us; speedup 1.0000x reference)
//
#include <hip/hip_runtime.h>

#define N_NODES 65536
#define B_G     16
#define NPG_    4096
#define H_H     2
#define D_D     64
#define HD      128
#define E_E     524288
#define D_OUT   64

// ---------------- degree / CSR build ----------------

__global__ void deg_kernel(const int* __restrict__ col, int* __restrict__ degi) {
    int e = blockIdx.x * 256 + threadIdx.x;
    if (e < E_E) atomicAdd(&degi[col[e]], 1);
}

__global__ void dinv_kernel(const int* __restrict__ degi, float* __restrict__ dinv) {
    int n = blockIdx.x * 256 + threadIdx.x;
    if (n < N_NODES) {
        int d = degi[n];
        dinv[n] = (d > 0) ? (1.0f / sqrtf((float)d)) : 0.0f;
    }
}

__global__ void scan1(const int* __restrict__ degi, int* __restrict__ ptr,
                      int* __restrict__ bsums) {
    __shared__ int lds[256];
    int t = threadIdx.x;
    int i = blockIdx.x * 256 + t;
    int v = degi[i];
    lds[t] = v;
    __syncthreads();
    for (int off = 1; off < 256; off <<= 1) {
        int tmp = (t >= off) ? lds[t - off] : 0;
        __syncthreads();
        lds[t] += tmp;
        __syncthreads();
    }
    ptr[i] = lds[t] - v;                 // block-local exclusive
    if (t == 255) bsums[blockIdx.x] = lds[255];
}

__global__ void scan2(int* __restrict__ bsums) {
    __shared__ int lds[256];
    int t = threadIdx.x;
    int v = bsums[t];
    lds[t] = v;
    __syncthreads();
    for (int off = 1; off < 256; off <<= 1) {
        int tmp = (t >= off) ? lds[t - off] : 0;
        __syncthreads();
        lds[t] += tmp;
        __syncthreads();
    }
    bsums[t] = lds[t] - v;               // exclusive block offsets
}

__global__ void scan3(int* __restrict__ ptr, const int* __restrict__ bsums) {
    int i = blockIdx.x * 256 + threadIdx.x;
    ptr[i] += bsums[blockIdx.x];
    if (i == 0) ptr[N_NODES] = E_E;
}

__global__ void scatter_kernel(const int* __restrict__ row, const int* __restrict__ col,
                               const int* __restrict__ ptr, int* __restrict__ cursor,
                               const float* __restrict__ dinv,
                               int2* __restrict__ ep) {
    int e = blockIdx.x * 256 + threadIdx.x;
    if (e < E_E) {
        int c = col[e], r = row[e];
        int p = ptr[c] + atomicAdd(&cursor[c], 1);
        ep[p] = make_int2(r, __float_as_int(dinv[c] * dinv[r]));
    }
}

// ---------------- q/k projection + fused L2-normalize ----------------
// 2048 blocks x 256 thr; block handles 32 nodes (8 blocks/CU).
// wave 0: q head0 cols 0..63, wave 1: q head1, wave 2: k head0, wave 3: k head1.
__global__ __launch_bounds__(256) void proj_kernel(
    const float* __restrict__ x,
    const float* __restrict__ Wq, const float* __restrict__ bq,
    const float* __restrict__ Wk, const float* __restrict__ bk,
    float* __restrict__ qs, float* __restrict__ ks) {
    __shared__ float xl[32 * 64];
    int t = threadIdx.x;
    int nb = blockIdx.x;
    const float4* x4 = (const float4*)(x + (size_t)nb * 32 * 64);
    float4* xl4 = (float4*)xl;
    xl4[t] = x4[t];
    xl4[t + 256] = x4[t + 256];
    __syncthreads();

    int col = t & 127;
    const float* W = (t < 128) ? Wq : Wk;
    float bias = (t < 128) ? bq[col] : bk[col];
    float* outp = (t < 128) ? qs : ks;
    float wc[64];
#pragma unroll
    for (int kk = 0; kk < 64; ++kk) wc[kk] = W[kk * 128 + col];

    for (int i = 0; i < 32; ++i) {
        const float4* xr = (const float4*)(xl + i * 64);
        float a0 = 0.f, a1 = 0.f, a2 = 0.f, a3 = 0.f;
#pragma unroll
        for (int k4 = 0; k4 < 16; ++k4) {
            float4 v = xr[k4];
            a0 += v.x * wc[4 * k4];
            a1 += v.y * wc[4 * k4 + 1];
            a2 += v.z * wc[4 * k4 + 2];
            a3 += v.w * wc[4 * k4 + 3];
        }
        float acc = bias + ((a0 + a1) + (a2 + a3));
        float sq = acc * acc;
#pragma unroll
        for (int off = 32; off > 0; off >>= 1) sq += __shfl_xor(sq, off);
        outp[(size_t)(nb * 32 + i) * 128 + col] = acc * rsqrtf(sq);
    }
}

// ---------------- kvs = K^T X per (b,h); plus ksum, xsum ----------------
__global__ __launch_bounds__(256) void kvs_kernel(
    const float* __restrict__ ks, const float* __restrict__ x,
    float* __restrict__ kvs, float* __restrict__ ksum, float* __restrict__ xsum) {
    int bid = blockIdx.x;
    int chunk = bid & 7;
    int bh = bid >> 3;
    int b = bh >> 1, h = bh & 1;
    int t = threadIdx.x;
    int mrow = t >> 4, dcol = t & 15;
    int m0 = mrow * 4, d0 = dcol * 4;
    __shared__ float kl[32 * 64];
    __shared__ float xl[32 * 64];
    float acc[4][4] = {{0}};
    float ksacc[4] = {0, 0, 0, 0};
    float xsacc[4] = {0, 0, 0, 0};
    int node0 = b * NPG_ + chunk * 512;
    for (int s = 0; s < 16; ++s) {
        int nb = node0 + s * 32;
        for (int i = t; i < 512; i += 256) {
            int l = i >> 4, q = i & 15;
            ((float4*)kl)[i] = *(const float4*)(ks + (size_t)(nb + l) * 128 + h * 64 + q * 4);
        }
        const float4* xg = (const float4*)(x + (size_t)nb * 64);
        for (int i = t; i < 512; i += 256) ((float4*)xl)[i] = xg[i];
        __syncthreads();
        for (int l = 0; l < 32; ++l) {
            float4 kv = *(float4*)(kl + l * 64 + m0);
            float4 xv = *(float4*)(xl + l * 64 + d0);
            float kk[4] = {kv.x, kv.y, kv.z, kv.w};
            float xx[4] = {xv.x, xv.y, xv.z, xv.w};
#pragma unroll
            for (int i = 0; i < 4; ++i)
#pragma unroll
                for (int j = 0; j < 4; ++j) acc[i][j] += kk[i] * xx[j];
            if (dcol == 0) {
#pragma unroll
                for (int i = 0; i < 4; ++i) ksacc[i] += kk[i];
            }
            if (mrow == 0) {
#pragma unroll
                for (int j = 0; j < 4; ++j) xsacc[j] += xx[j];
            }
        }
        __syncthreads();
    }
#pragma unroll
    for (int i = 0; i < 4; ++i)
#pragma unroll
        for (int j = 0; j < 4; ++j)
            atomicAdd(&kvs[(bh * 64 + m0 + i) * 64 + d0 + j], acc[i][j]);
    if (dcol == 0) {
#pragma unroll
        for (int i = 0; i < 4; ++i) atomicAdd(&ksum[bh * 64 + m0 + i], ksacc[i]);
    }
    if (mrow == 0 && h == 0) {
#pragma unroll
        for (int j = 0; j < 4; ++j) atomicAdd(&xsum[b * 64 + d0 + j], xsacc[j]);
    }
}

// ---------------- attention output: block = 128 nodes x 1 head ----------------
__global__ __launch_bounds__(256) void attn_kernel(
    const float* __restrict__ qs, const float* __restrict__ kvs,
    const float* __restrict__ ksum, const float* __restrict__ xsum,
    float* __restrict__ attn) {
    __shared__ float ql[128 * 64];
    int bid = blockIdx.x;
    int h = bid & 1;
    int nb = (bid >> 1) * 128;
    int b = nb >> 12;
    int bh = b * 2 + h;
    int t = threadIdx.x;
    int lane = t & 63;
    for (int i = t; i < 128 * 16; i += 256) {
        int r = i >> 4, q4 = i & 15;
        ((float4*)ql)[i] = *(const float4*)(qs + (size_t)(nb + r) * 128 + h * 64 + q4 * 4);
    }
    float kvreg[64];
    const float* kvp = kvs + bh * 4096 + lane;
#pragma unroll
    for (int m = 0; m < 64; ++m) kvreg[m] = kvp[m * 64];
    float ksreg = ksum[bh * 64 + lane];
    float xs_d = xsum[b * 64 + lane];
    __syncthreads();
    int nslot = t >> 6;
    for (int nn = 0; nn < 32; ++nn) {
        int node = nn * 4 + nslot;
        const float* qrow = ql + node * 64;
        float p = qrow[lane] * ksreg;
#pragma unroll
        for (int off = 32; off > 0; off >>= 1) p += __shfl_xor(p, off);
        float den = p + 16.0f;
        float acc = 0.f;
#pragma unroll
        for (int m4 = 0; m4 < 16; ++m4) {
            float4 qv = *(const float4*)(qrow + m4 * 4);
            acc += qv.x * kvreg[4 * m4] + qv.y * kvreg[4 * m4 + 1] +
                   qv.z * kvreg[4 * m4 + 2] + qv.w * kvreg[4 * m4 + 3];
        }
        attn[(size_t)(nb + node) * 128 + h * 64 + lane] = (acc + xs_d) / den;
    }
}

// ---------------- GCN step: one wave per node, float2 per lane ----------------
// Batched edge pipeline: 16 clamped index loads, then 16 independent gathers
// (2 latency round-trips instead of ~deg). Slots >= cnt clamp to last edge
// (hot line) with val=0. XCD-chunked swizzle keeps each graph's gather set in L2.
template <int FIRST>
__global__ __launch_bounds__(256) void gcn_kernel(
    const float* __restrict__ xin, const float* __restrict__ attn,
    const int* __restrict__ ptr, const int2* __restrict__ ep,
    float* __restrict__ xout) {
    int bid = blockIdx.x;
    int lbid = (bid & 7) * (N_NODES / 4 / 8) + (bid >> 3);
    int t = threadIdx.x;
    int n = lbid * 4 + (t >> 6);
    int lane = t & 63;
    int c = lane * 2;
    int cx = FIRST ? (c & 63) : c;
    const int ldx = FIRST ? 64 : 128;
    int e0 = ptr[n], e1 = ptr[n + 1];
    int cnt = e1 - e0;
    float2 acc = make_float2(0.f, 0.f);

    int2 q[16];
#pragma unroll
    for (int i = 0; i < 16; ++i) {
        int ee = e0 + i;
        if (ee > e1 - 1) ee = e1 - 1;
        if (ee < 0) ee = 0;
        q[i] = ep[ee];
    }
#pragma unroll
    for (int i = 0; i < 16; ++i) {
        float v = (i < cnt) ? __int_as_float(q[i].y) : 0.0f;
        float2 xv = *(const float2*)(xin + (size_t)q[i].x * ldx + cx);
        acc.x += v * xv.x;
        acc.y += v * xv.y;
    }
    for (int e = e0 + 16; e < e1; ++e) {           // rare tail (P(deg>16)~0.4%)
        int2 qq = ep[e];
        float v = __int_as_float(qq.y);
        float2 xv = *(const float2*)(xin + (size_t)qq.x * ldx + cx);
        acc.x += v * xv.x;
        acc.y += v * xv.y;
    }

    float2 self = *(const float2*)(xin + (size_t)n * ldx + cx);
    size_t idx = (size_t)n * 128 + c;
    float2 at = *(const float2*)(attn + idx);
    float2 o;
    o.x = self.x + 0.5f * acc.x + 0.5f * at.x;
    o.y = self.y + 0.5f * acc.y + 0.5f * at.y;
    *(float2*)(xout + idx) = o;
}

// ---------------- output projection: (xs @ Wo + bo)/H ----------------
__global__ __launch_bounds__(256) void out_kernel(
    const float* __restrict__ xs, const float* __restrict__ Wo,
    const float* __restrict__ bo, float* __restrict__ out) {
    __shared__ float wl[128 * 64];
    __shared__ float bl[64];
    int t = threadIdx.x;
    for (int i = t; i < 128 * 64 / 4; i += 256) ((float4*)wl)[i] = ((const float4*)Wo)[i];
    if (t < 64) bl[t] = bo[t];
    __syncthreads();
    int j = t & 63, ng = t >> 6;
    int nbase = blockIdx.x * 64;
    for (int it = 0; it < 16; ++it) {
        int n = nbase + it * 4 + ng;
        const float4* xr4 = (const float4*)(xs + (size_t)n * 128);
        float acc = bl[j];
#pragma unroll
        for (int k4 = 0; k4 < 32; ++k4) {
            float4 v = xr4[k4];
            acc += v.x * wl[(4 * k4 + 0) * 64 + j] + v.y * wl[(4 * k4 + 1) * 64 + j] +
                   v.z * wl[(4 * k4 + 2) * 64 + j] + v.w * wl[(4 * k4 + 3) * 64 + j];
        }
        out[(size_t)n * 64 + j] = acc * 0.5f;   // 1/H
    }
}

// ---------------- launch ----------------

extern "C" void kernel_launch(void* const* d_in, const int* in_sizes, int n_in,
                              void* d_out, int out_size, void* d_ws, size_t ws_size,
                              hipStream_t stream) {
    const float* x  = (const float*)d_in[0];
    const int* ei   = (const int*)d_in[1];
    const float* Wq = (const float*)d_in[3];
    const float* bq = (const float*)d_in[4];
    const float* Wk = (const float*)d_in[5];
    const float* bk = (const float*)d_in[6];
    const float* Wo = (const float*)d_in[7];
    const float* bo = (const float*)d_in[8];
    float* out = (float*)d_out;

    const int* row = ei;
    const int* col = ei + E_E;

    // workspace layout (floats; ep is int2 and 8B-aligned by even float offset)
    float* qs    = (float*)d_ws;                       // N*HD (later xsA)
    float* ksatt = qs + (size_t)N_NODES * HD;          // N*HD (ks, later attn)
    float* xsB   = ksatt + (size_t)N_NODES * HD;       // N*HD
    int2*  ep    = (int2*)(xsB + (size_t)N_NODES * HD);// E (8B each)
    float* kvs   = (float*)(ep + E_E);                 // 32*64*64
    float* ksum  = kvs + 131072;                       // 2048
    float* xsum  = ksum + 2048;                        // 1024
    float* dinv  = xsum + 1024;                        // N
    int* degi    = (int*)(dinv + N_NODES);             // N
    int* ptr     = degi + N_NODES;                     // N+1
    int* bsums   = ptr + N_NODES + 1;                  // 256

    hipMemsetAsync(degi, 0, (size_t)N_NODES * 4, stream);
    hipMemsetAsync(kvs, 0, (size_t)(131072 + 2048 + 1024) * 4, stream);

    // CSR build
    deg_kernel<<<E_E / 256, 256, 0, stream>>>(col, degi);
    dinv_kernel<<<N_NODES / 256, 256, 0, stream>>>(degi, dinv);
    scan1<<<N_NODES / 256, 256, 0, stream>>>(degi, ptr, bsums);
    scan2<<<1, 256, 0, stream>>>(bsums);
    scan3<<<N_NODES / 256, 256, 0, stream>>>(ptr, bsums);
    hipMemsetAsync(degi, 0, (size_t)N_NODES * 4, stream);   // reuse as cursor
    scatter_kernel<<<E_E / 256, 256, 0, stream>>>(row, col, ptr, degi, dinv, ep);

    // projections (norm fused)
    proj_kernel<<<2048, 256, 0, stream>>>(x, Wq, bq, Wk, bk, qs, ksatt);

    // attention (loop-invariant)
    kvs_kernel<<<256, 256, 0, stream>>>(ksatt, x, kvs, ksum, xsum);
    attn_kernel<<<1024, 256, 0, stream>>>(qs, kvs, ksum, xsum, ksatt);

    // 4 GCN steps; iter 1 reads x directly (xs0 = broadcast x), ping-pong after
    gcn_kernel<1><<<N_NODES / 4, 256, 0, stream>>>(x, ksatt, ptr, ep, qs);
    gcn_kernel<0><<<N_NODES / 4, 256, 0, stream>>>(qs, ksatt, ptr, ep, xsB);
    gcn_kernel<0><<<N_NODES / 4, 256, 0, stream>>>(xsB, ksatt, ptr, ep, qs);
    gcn_kernel<0><<<N_NODES / 4, 256, 0, stream>>>(qs, ksatt, ptr, ep, xsB);

    // output projection
    out_kernel<<<1024, 256, 0, stream>>>(xsB, Wo, bo, out);
}

// Round 5
// 522.281 us; speedup vs baseline: 1.2745x; 1.2745x over previous
//
#include <hip/hip_runtime.h>

#define N_NODES 65536
#define B_G     16
#define NPG_    4096
#define H_H     2
#define D_D     64
#define HD      128
#define E_E     524288
#define D_OUT   64

// ---------------- degree / CSR build ----------------

__global__ void deg_kernel(const int* __restrict__ col, int* __restrict__ degi) {
    int e = blockIdx.x * 256 + threadIdx.x;
    if (e < E_E) atomicAdd(&degi[col[e]], 1);
}

__global__ void dinv_kernel(const int* __restrict__ degi, float* __restrict__ dinv) {
    int n = blockIdx.x * 256 + threadIdx.x;
    if (n < N_NODES) {
        int d = degi[n];
        dinv[n] = (d > 0) ? (1.0f / sqrtf((float)d)) : 0.0f;
    }
}

__global__ void scan1(const int* __restrict__ degi, int* __restrict__ ptr,
                      int* __restrict__ bsums) {
    __shared__ int lds[256];
    int t = threadIdx.x;
    int i = blockIdx.x * 256 + t;
    int v = degi[i];
    lds[t] = v;
    __syncthreads();
    for (int off = 1; off < 256; off <<= 1) {
        int tmp = (t >= off) ? lds[t - off] : 0;
        __syncthreads();
        lds[t] += tmp;
        __syncthreads();
    }
    ptr[i] = lds[t] - v;
    if (t == 255) bsums[blockIdx.x] = lds[255];
}

__global__ void scan2(int* __restrict__ bsums) {
    __shared__ int lds[256];
    int t = threadIdx.x;
    int v = bsums[t];
    lds[t] = v;
    __syncthreads();
    for (int off = 1; off < 256; off <<= 1) {
        int tmp = (t >= off) ? lds[t - off] : 0;
        __syncthreads();
        lds[t] += tmp;
        __syncthreads();
    }
    bsums[t] = lds[t] - v;
}

__global__ void scan3(int* __restrict__ ptr, const int* __restrict__ bsums) {
    int i = blockIdx.x * 256 + threadIdx.x;
    ptr[i] += bsums[blockIdx.x];
    if (i == 0) ptr[N_NODES] = E_E;
}

__global__ void scatter_kernel(const int* __restrict__ row, const int* __restrict__ col,
                               const int* __restrict__ ptr, int* __restrict__ cursor,
                               const float* __restrict__ dinv,
                               int2* __restrict__ ep) {
    int e = blockIdx.x * 256 + threadIdx.x;
    if (e < E_E) {
        int c = col[e], r = row[e];
        int p = ptr[c] + atomicAdd(&cursor[c], 1);
        ep[p] = make_int2(r, __float_as_int(dinv[c] * dinv[r]));
    }
}

// ---------------- q/k projection + fused L2-normalize ----------------
// 2048 blocks x 256 thr; 32 nodes/block. W column held in float4 regs
// (launch_bounds(256,4) -> <=128 VGPR so wc4[16] stays in registers).
__global__ __launch_bounds__(256, 4) void proj_kernel(
    const float* __restrict__ x,
    const float* __restrict__ Wq, const float* __restrict__ bq,
    const float* __restrict__ Wk, const float* __restrict__ bk,
    float* __restrict__ qs, float* __restrict__ ks) {
    __shared__ float xl[32 * 64];
    int t = threadIdx.x;
    int nb = blockIdx.x;
    const float4* x4 = (const float4*)(x + (size_t)nb * 32 * 64);
    float4* xl4 = (float4*)xl;
    xl4[t] = x4[t];
    xl4[t + 256] = x4[t + 256];

    int col = t & 127;
    const float* W = (t < 128) ? Wq : Wk;
    float bias = (t < 128) ? bq[col] : bk[col];
    float* outp = (t < 128) ? qs : ks;
    float4 wc4[16];
#pragma unroll
    for (int kk = 0; kk < 16; ++kk) {
        wc4[kk].x = W[(4 * kk + 0) * 128 + col];
        wc4[kk].y = W[(4 * kk + 1) * 128 + col];
        wc4[kk].z = W[(4 * kk + 2) * 128 + col];
        wc4[kk].w = W[(4 * kk + 3) * 128 + col];
    }
    __syncthreads();

    for (int i = 0; i < 32; ++i) {
        const float4* xr = (const float4*)(xl + i * 64);
        float a0 = 0.f, a1 = 0.f, a2 = 0.f, a3 = 0.f;
#pragma unroll
        for (int k4 = 0; k4 < 16; ++k4) {
            float4 v = xr[k4];
            a0 += v.x * wc4[k4].x;
            a1 += v.y * wc4[k4].y;
            a2 += v.z * wc4[k4].z;
            a3 += v.w * wc4[k4].w;
        }
        float acc = bias + ((a0 + a1) + (a2 + a3));
        float sq = acc * acc;
#pragma unroll
        for (int off = 32; off > 0; off >>= 1) sq += __shfl_xor(sq, off);
        outp[(size_t)(nb * 32 + i) * 128 + col] = acc * rsqrtf(sq);
    }
}

// ---------------- kvs = K^T X per (b,h); plus ksum, xsum ----------------
// 1024 blocks: (bh, 32 chunks of 128 nodes) -> 4 blocks/CU.
__global__ __launch_bounds__(256) void kvs_kernel(
    const float* __restrict__ ks, const float* __restrict__ x,
    float* __restrict__ kvs, float* __restrict__ ksum, float* __restrict__ xsum) {
    int bid = blockIdx.x;
    int chunk = bid & 31;
    int bh = bid >> 5;
    int b = bh >> 1, h = bh & 1;
    int t = threadIdx.x;
    int mrow = t >> 4, dcol = t & 15;
    int m0 = mrow * 4, d0 = dcol * 4;
    __shared__ float kl[32 * 64];
    __shared__ float xl[32 * 64];
    float acc[4][4] = {{0}};
    float ksacc[4] = {0, 0, 0, 0};
    float xsacc[4] = {0, 0, 0, 0};
    int node0 = b * NPG_ + chunk * 128;
    for (int s = 0; s < 4; ++s) {
        int nb = node0 + s * 32;
        for (int i = t; i < 512; i += 256) {
            int l = i >> 4, q = i & 15;
            ((float4*)kl)[i] = *(const float4*)(ks + (size_t)(nb + l) * 128 + h * 64 + q * 4);
        }
        const float4* xg = (const float4*)(x + (size_t)nb * 64);
        for (int i = t; i < 512; i += 256) ((float4*)xl)[i] = xg[i];
        __syncthreads();
        for (int l = 0; l < 32; ++l) {
            float4 kv = *(float4*)(kl + l * 64 + m0);
            float4 xv = *(float4*)(xl + l * 64 + d0);
            float kk[4] = {kv.x, kv.y, kv.z, kv.w};
            float xx[4] = {xv.x, xv.y, xv.z, xv.w};
#pragma unroll
            for (int i = 0; i < 4; ++i)
#pragma unroll
                for (int j = 0; j < 4; ++j) acc[i][j] += kk[i] * xx[j];
            if (dcol == 0) {
#pragma unroll
                for (int i = 0; i < 4; ++i) ksacc[i] += kk[i];
            }
            if (mrow == 0) {
#pragma unroll
                for (int j = 0; j < 4; ++j) xsacc[j] += xx[j];
            }
        }
        __syncthreads();
    }
#pragma unroll
    for (int i = 0; i < 4; ++i)
#pragma unroll
        for (int j = 0; j < 4; ++j)
            atomicAdd(&kvs[(bh * 64 + m0 + i) * 64 + d0 + j], acc[i][j]);
    if (dcol == 0) {
#pragma unroll
        for (int i = 0; i < 4; ++i) atomicAdd(&ksum[bh * 64 + m0 + i], ksacc[i]);
    }
    if (mrow == 0 && h == 0) {
#pragma unroll
        for (int j = 0; j < 4; ++j) atomicAdd(&xsum[b * 64 + d0 + j], xsacc[j]);
    }
}

// ---------------- attention output: block = 128 nodes x 1 head ----------------
__global__ __launch_bounds__(256) void attn_kernel(
    const float* __restrict__ qs, const float* __restrict__ kvs,
    const float* __restrict__ ksum, const float* __restrict__ xsum,
    float* __restrict__ attn) {
    __shared__ float ql[128 * 64];
    int bid = blockIdx.x;
    int h = bid & 1;
    int nb = (bid >> 1) * 128;
    int b = nb >> 12;
    int bh = b * 2 + h;
    int t = threadIdx.x;
    int lane = t & 63;
    for (int i = t; i < 128 * 16; i += 256) {
        int r = i >> 4, q4 = i & 15;
        ((float4*)ql)[i] = *(const float4*)(qs + (size_t)(nb + r) * 128 + h * 64 + q4 * 4);
    }
    float kvreg[64];
    const float* kvp = kvs + bh * 4096 + lane;
#pragma unroll
    for (int m = 0; m < 64; ++m) kvreg[m] = kvp[m * 64];
    float ksreg = ksum[bh * 64 + lane];
    float xs_d = xsum[b * 64 + lane];
    __syncthreads();
    int nslot = t >> 6;
    for (int nn = 0; nn < 32; ++nn) {
        int node = nn * 4 + nslot;
        const float* qrow = ql + node * 64;
        float p = qrow[lane] * ksreg;
#pragma unroll
        for (int off = 32; off > 0; off >>= 1) p += __shfl_xor(p, off);
        float den = p + 16.0f;
        float acc = 0.f;
#pragma unroll
        for (int m4 = 0; m4 < 16; ++m4) {
            float4 qv = *(const float4*)(qrow + m4 * 4);
            acc += qv.x * kvreg[4 * m4] + qv.y * kvreg[4 * m4 + 1] +
                   qv.z * kvreg[4 * m4 + 2] + qv.w * kvreg[4 * m4 + 3];
        }
        attn[(size_t)(nb + node) * 128 + h * 64 + lane] = (acc + xs_d) / den;
    }
}

// ---------------- GCN step: 2 nodes per wave (32 lanes x float4 each) ----------------
// 8/8/tail batched gathers (avg deg 8 -> usually one batch, no 2x padding waste).
// XCD-chunked swizzle keeps each graph's 2MB gather window in its XCD's L2.
template <int FIRST>
__global__ __launch_bounds__(256) void gcn_kernel(
    const float* __restrict__ xin, const float* __restrict__ attn,
    const int* __restrict__ ptr, const int2* __restrict__ ep,
    float* __restrict__ xout) {
    int bid = blockIdx.x;                                  // 8192 blocks, 8 nodes each
    int lbid = (bid & 7) * (N_NODES / 8 / 8) + (bid >> 3);
    int t = threadIdx.x;
    int n = lbid * 8 + (t >> 5);
    int lq = t & 31;
    int c4 = lq * 4;
    int cx = FIRST ? (c4 & 63) : c4;
    const int ldx = FIRST ? 64 : 128;
    int e0 = ptr[n], e1 = ptr[n + 1];
    int cnt = e1 - e0;
    float4 acc = make_float4(0.f, 0.f, 0.f, 0.f);

    {
        int2 q[8];
#pragma unroll
        for (int i = 0; i < 8; ++i) {
            int ee = e0 + i;
            if (ee > e1 - 1) ee = e1 - 1;
            if (ee < 0) ee = 0;
            q[i] = ep[ee];
        }
#pragma unroll
        for (int i = 0; i < 8; ++i) {
            float v = (i < cnt) ? __int_as_float(q[i].y) : 0.0f;
            float4 xv = *(const float4*)(xin + (size_t)q[i].x * ldx + cx);
            acc.x += v * xv.x; acc.y += v * xv.y;
            acc.z += v * xv.z; acc.w += v * xv.w;
        }
    }
    if (cnt > 8) {
        int2 q[8];
#pragma unroll
        for (int i = 0; i < 8; ++i) {
            int ee = e0 + 8 + i;
            if (ee > e1 - 1) ee = e1 - 1;
            q[i] = ep[ee];
        }
#pragma unroll
        for (int i = 0; i < 8; ++i) {
            float v = (8 + i < cnt) ? __int_as_float(q[i].y) : 0.0f;
            float4 xv = *(const float4*)(xin + (size_t)q[i].x * ldx + cx);
            acc.x += v * xv.x; acc.y += v * xv.y;
            acc.z += v * xv.z; acc.w += v * xv.w;
        }
        for (int e = e0 + 16; e < e1; ++e) {
            int2 qq = ep[e];
            float v = __int_as_float(qq.y);
            float4 xv = *(const float4*)(xin + (size_t)qq.x * ldx + cx);
            acc.x += v * xv.x; acc.y += v * xv.y;
            acc.z += v * xv.z; acc.w += v * xv.w;
        }
    }

    float4 self = *(const float4*)(xin + (size_t)n * ldx + cx);
    size_t idx = (size_t)n * 128 + c4;
    float4 at = *(const float4*)(attn + idx);
    float4 o;
    o.x = self.x + 0.5f * acc.x + 0.5f * at.x;
    o.y = self.y + 0.5f * acc.y + 0.5f * at.y;
    o.z = self.z + 0.5f * acc.z + 0.5f * at.z;
    o.w = self.w + 0.5f * acc.w + 0.5f * at.w;
    *(float4*)(xout + idx) = o;
}

// ---------------- output projection: (xs @ Wo + bo)/H ----------------
// Wo transposed+padded in LDS (row stride 132 floats): each lane owns out col j,
// reads its column as ds_read_b128 (8-way spread = b128 floor). 4-node register
// blocking amortizes W reads; xs rows via wave-broadcast global float4 loads.
__global__ __launch_bounds__(256) void out_kernel(
    const float* __restrict__ xs, const float* __restrict__ Wo,
    const float* __restrict__ bo, float* __restrict__ out) {
    __shared__ float wlt[64 * 132];
    int t = threadIdx.x;
    for (int i = t; i < 8192; i += 256) {
        int k = i >> 6, j = i & 63;
        wlt[j * 132 + k] = Wo[i];
    }
    __syncthreads();
    int j = t & 63, ng = t >> 6;
    float bias = bo[j];
    const float* wj = wlt + j * 132;
    int nbase = blockIdx.x * 64 + ng * 16;
    for (int g = 0; g < 4; ++g) {
        int n0 = nbase + g * 4;
        const float4* xr0 = (const float4*)(xs + (size_t)(n0 + 0) * 128);
        const float4* xr1 = (const float4*)(xs + (size_t)(n0 + 1) * 128);
        const float4* xr2 = (const float4*)(xs + (size_t)(n0 + 2) * 128);
        const float4* xr3 = (const float4*)(xs + (size_t)(n0 + 3) * 128);
        float a0 = 0.f, a1 = 0.f, a2 = 0.f, a3 = 0.f;
#pragma unroll 4
        for (int k4 = 0; k4 < 32; ++k4) {
            float4 w = *(const float4*)(wj + k4 * 4);
            float4 v0 = xr0[k4], v1 = xr1[k4], v2 = xr2[k4], v3 = xr3[k4];
            a0 += w.x * v0.x + w.y * v0.y + w.z * v0.z + w.w * v0.w;
            a1 += w.x * v1.x + w.y * v1.y + w.z * v1.z + w.w * v1.w;
            a2 += w.x * v2.x + w.y * v2.y + w.z * v2.z + w.w * v2.w;
            a3 += w.x * v3.x + w.y * v3.y + w.z * v3.z + w.w * v3.w;
        }
        out[(size_t)(n0 + 0) * 64 + j] = (bias + a0) * 0.5f;
        out[(size_t)(n0 + 1) * 64 + j] = (bias + a1) * 0.5f;
        out[(size_t)(n0 + 2) * 64 + j] = (bias + a2) * 0.5f;
        out[(size_t)(n0 + 3) * 64 + j] = (bias + a3) * 0.5f;
    }
}

// ---------------- launch ----------------

extern "C" void kernel_launch(void* const* d_in, const int* in_sizes, int n_in,
                              void* d_out, int out_size, void* d_ws, size_t ws_size,
                              hipStream_t stream) {
    const float* x  = (const float*)d_in[0];
    const int* ei   = (const int*)d_in[1];
    const float* Wq = (const float*)d_in[3];
    const float* bq = (const float*)d_in[4];
    const float* Wk = (const float*)d_in[5];
    const float* bk = (const float*)d_in[6];
    const float* Wo = (const float*)d_in[7];
    const float* bo = (const float*)d_in[8];
    float* out = (float*)d_out;

    const int* row = ei;
    const int* col = ei + E_E;

    float* qs    = (float*)d_ws;                       // N*HD (later xsA)
    float* ksatt = qs + (size_t)N_NODES * HD;          // N*HD (ks, later attn)
    float* xsB   = ksatt + (size_t)N_NODES * HD;       // N*HD
    int2*  ep    = (int2*)(xsB + (size_t)N_NODES * HD);// E
    float* kvs   = (float*)(ep + E_E);                 // 32*64*64
    float* ksum  = kvs + 131072;                       // 2048
    float* xsum  = ksum + 2048;                        // 1024
    float* dinv  = xsum + 1024;                        // N
    int* degi    = (int*)(dinv + N_NODES);             // N
    int* ptr     = degi + N_NODES;                     // N+1
    int* bsums   = ptr + N_NODES + 1;                  // 256

    hipMemsetAsync(degi, 0, (size_t)N_NODES * 4, stream);
    hipMemsetAsync(kvs, 0, (size_t)(131072 + 2048 + 1024) * 4, stream);

    deg_kernel<<<E_E / 256, 256, 0, stream>>>(col, degi);
    dinv_kernel<<<N_NODES / 256, 256, 0, stream>>>(degi, dinv);
    scan1<<<N_NODES / 256, 256, 0, stream>>>(degi, ptr, bsums);
    scan2<<<1, 256, 0, stream>>>(bsums);
    scan3<<<N_NODES / 256, 256, 0, stream>>>(ptr, bsums);
    hipMemsetAsync(degi, 0, (size_t)N_NODES * 4, stream);
    scatter_kernel<<<E_E / 256, 256, 0, stream>>>(row, col, ptr, degi, dinv, ep);

    proj_kernel<<<2048, 256, 0, stream>>>(x, Wq, bq, Wk, bk, qs, ksatt);

    kvs_kernel<<<1024, 256, 0, stream>>>(ksatt, x, kvs, ksum, xsum);
    attn_kernel<<<1024, 256, 0, stream>>>(qs, kvs, ksum, xsum, ksatt);

    gcn_kernel<1><<<N_NODES / 8, 256, 0, stream>>>(x, ksatt, ptr, ep, qs);
    gcn_kernel<0><<<N_NODES / 8, 256, 0, stream>>>(qs, ksatt, ptr, ep, xsB);
    gcn_kernel<0><<<N_NODES / 8, 256, 0, stream>>>(xsB, ksatt, ptr, ep, qs);
    gcn_kernel<0><<<N_NODES / 8, 256, 0, stream>>>(qs, ksatt, ptr, ep, xsB);

    out_kernel<<<1024, 256, 0, stream>>>(xsB, Wo, bo, out);
}